// Round 2
// baseline (645.352 us; speedup 1.0000x reference)
//
#include <hip/hip_runtime.h>
#include <math.h>

// PrototypicalLoss: B=8192, N=64, D=256 fp32.
// One wave (64 lanes) per batch element; 4 waves per 256-thread block.
// Only support rows with label==1 are read (~50% of the 512 MiB input),
// each as a full contiguous 1 KiB row (float4/lane, 64 lanes).
// Fused: per-block LDS combine of the 4 distances + one atomicAdd per block
// into d_out (pre-zeroed via hipMemsetAsync). 2048 same-address atomics.

__global__ __launch_bounds__(256) void proto_loss_kernel(
    const float* __restrict__ query,    // (B, 256)
    const float* __restrict__ support,  // (B, 64, 256)
    const int*   __restrict__ labels,   // (B, 64)
    float* __restrict__ out,            // scalar, pre-zeroed
    int B)
{
    const int lane = threadIdx.x & 63;
    const int wv   = threadIdx.x >> 6;
    const int b    = blockIdx.x * 4 + wv;

    __shared__ float sm[4];

    float dist = 0.0f;
    if (b < B) {
        // one label per lane -> wave-uniform 64-bit mask (SGPR)
        const int lab = labels[(size_t)b * 64 + lane];
        const unsigned long long m = __ballot(lab == 1);
        const int count = __popcll(m);

        // support rows for this b, 64 float4 per row
        const float4* srow = (const float4*)(support + (size_t)b * 64 * 256);

        float4 acc = make_float4(0.f, 0.f, 0.f, 0.f);
        unsigned long long mm = m;
        while (mm) {                   // wave-uniform loop, scalar mask chain
            const int n = __builtin_ctzll(mm);
            mm &= (mm - 1);
            const float4 v = srow[(size_t)n * 64 + lane];
            acc.x += v.x; acc.y += v.y; acc.z += v.z; acc.w += v.w;
        }

        float4 proto;
        if (count > 0) {               // wave-uniform branch
            const float inv = 1.0f / (float)count;
            proto = make_float4(acc.x * inv, acc.y * inv, acc.z * inv, acc.w * inv);
        } else {
            proto = srow[lane];        // fallback: support[b, 0, :]
        }

        const float4 q = ((const float4*)(query + (size_t)b * 256))[lane];
        const float dx = q.x - proto.x;
        const float dy = q.y - proto.y;
        const float dz = q.z - proto.z;
        const float dw = q.w - proto.w;
        float ss = dx * dx + dy * dy + dz * dz + dw * dw;

        #pragma unroll
        for (int off = 32; off > 0; off >>= 1)
            ss += __shfl_down(ss, off, 64);

        dist = sqrtf(ss + 1e-8f);      // valid in lane 0
    }

    if (lane == 0) sm[wv] = dist;
    __syncthreads();
    if (threadIdx.x == 0) {
        const float local = (sm[0] + sm[1] + sm[2] + sm[3]) / (float)B;
        atomicAdd(out, local);         // device-scope, cross-XCD safe
    }
}

extern "C" void kernel_launch(void* const* d_in, const int* in_sizes, int n_in,
                              void* d_out, int out_size, void* d_ws, size_t ws_size,
                              hipStream_t stream) {
    const float* query   = (const float*)d_in[0];   // (B, D) fp32
    const float* support = (const float*)d_in[1];   // (B, N, D) fp32
    const int*   labels  = (const int*)d_in[2];     // (B, N) int32
    float* out = (float*)d_out;

    const int n_q = in_sizes[0];
    const int n_s = in_sizes[1];
    const int n_l = in_sizes[2];
    const int D = n_s / n_l;        // 256
    const int B = n_q / D;          // 8192
    (void)n_in; (void)out_size; (void)d_ws; (void)ws_size;

    // d_out is poisoned 0xAA before every timed launch -> zero it (capturable)
    hipMemsetAsync(out, 0, sizeof(float), stream);

    const int blocks = (B + 3) / 4; // 4 waves (batch elems) per 256-thread block
    proto_loss_kernel<<<blocks, 256, 0, stream>>>(query, support, labels, out, B);
}